// Round 7
// baseline (44.017 us; speedup 1.0000x reference)
//
#include <hip/hip_runtime.h>

// FlowWarpConsistencyLoss: B=16, C=3, H=W=512, flow 2x128x128.
// Single fused pass: block = 64x32 output tile; stage 120x80 gray(next) tile
// (computed on the fly from f32 next, OOB->0) as fp16 in LDS + 10 flow rows
// (f32); all warp gathers hit LDS; per-block partial -> d_ws slot.
// Then one single-block reduce -> out.
// R6->R7: fused pad_gray pass into loss staging (kills 10.6MB intermediate
// write + 50MB re-read pass + 1 launch + 1 barrier). Tile overlap re-reads of
// next (~4.7x) come from L2/L3 under the HBM-bound prev stream.
// fp16 error budget: gray in [0,1], |err|<=5e-4 per corner, << 3.77e-3 thresh.

typedef _Float16 half4v __attribute__((ext_vector_type(4)));

constexpr int B  = 16;
constexpr int H  = 512;
constexpr int W  = 512;
constexpr int FH = 128;
constexpr int FW = 128;
constexpr int HW  = H * W;
constexpr int IMG = 3 * HW;
constexpr int FHW = FH * FW;
constexpr float EPS = 0.001f;

constexpr int TX = 64, TY = 32;     // output tile per block
constexpr int TW = 120, TH = 80;    // staged tile (halo 24; |disp|~N(0,4px))
constexpr int FROWS  = 10;
constexpr int FLOW_F = 2 * FROWS * FW;

constexpr int NB = 2048;            // blocks (16 images x 128 tiles)

__device__ __forceinline__ float gray3(const float* __restrict__ img, int off) {
    return 0.299f * img[off] + 0.587f * img[HW + off] + 0.114f * img[2 * HW + off];
}

// ---------------- fused warp + loss ----------------
__global__ __launch_bounds__(256) void loss_kernel(
    const float* __restrict__ prev, const float* __restrict__ nxt,
    const float* __restrict__ flow, double* __restrict__ psum,
    unsigned int* __restrict__ pcnt)
{
    __shared__ __align__(16) _Float16 smh[TW * TH];   // 19.2 KB
    __shared__ __align__(16) float    smf[FLOW_F];    // 10 KB

    // XCD-chunked: 8 XCDs x 256 contiguous blocks (= 2 images each).
    const int bid = ((blockIdx.x & 7) << 8) | (blockIdx.x >> 3);
    const int b   = bid >> 7;              // 128 tiles per image
    const int t   = bid & 127;
    const int tx  = t & 7;                 // 8 x-tiles (64 wide)
    const int ty  = t >> 3;                // 16 y-tiles (32 tall)
    const int x0t = tx * TX;
    const int y0t = ty * TY;

    const float fr = (float)(127.0 / 511.0);
    const int fy_lo = (int)((float)y0t * fr);

    const float* __restrict__ nb = nxt + (long)b * IMG;

    // ---- stage gray(next) tile: y in [y0t-24, y0t+56), x in [x0t-24, x0t+96)
    // computed on the fly from f32 next; OOB -> 0 (matches per-corner zeroing).
    for (int it = threadIdx.x; it < TH * (TW / 4); it += 256) {
        const int r  = it / (TW / 4), c = it - r * (TW / 4);
        const int sy = y0t - 24 + r;
        const int sx = x0t - 24 + c * 4;
        half4v hv = (half4v)0;
        if ((unsigned)sy < (unsigned)H && (unsigned)sx <= (unsigned)(W - 4)) {
            const float* __restrict__ p = nb + sy * W + sx;
            const float4 rr = *(const float4*)(p);
            const float4 gg = *(const float4*)(p + HW);
            const float4 bl = *(const float4*)(p + 2 * HW);
            hv[0] = (_Float16)(0.299f * rr.x + 0.587f * gg.x + 0.114f * bl.x);
            hv[1] = (_Float16)(0.299f * rr.y + 0.587f * gg.y + 0.114f * bl.y);
            hv[2] = (_Float16)(0.299f * rr.z + 0.587f * gg.z + 0.114f * bl.z);
            hv[3] = (_Float16)(0.299f * rr.w + 0.587f * gg.w + 0.114f * bl.w);
        }
        *(half4v*)(smh + r * TW + c * 4) = hv;
    }
    // ---- stage 10 flow rows (u then v)
    {
        const float* __restrict__ fsrc = flow + (long)b * 2 * FHW;
        for (int it = threadIdx.x; it < 2 * FROWS * (FW / 4); it += 256) {
            const int c    = it / (FROWS * (FW / 4));
            const int rr   = (it - c * (FROWS * (FW / 4))) >> 5;
            const int c4   = it & 31;
            const int frow = min(fy_lo + rr, FH - 1);
            const float4 v = *(const float4*)(fsrc + c * FHW + frow * FW + c4 * 4);
            *(float4*)(smf + c * (FROWS * FW) + rr * FW + c4 * 4) = v;
        }
    }

    // ---- prev grayscale: thread = 4 consecutive x in rows yl and yl+16
    const int xq = threadIdx.x & 15;
    const int yl = threadIdx.x >> 4;
    const int xb = x0t + xq * 4;

    float pg[2][4];
    #pragma unroll
    for (int k = 0; k < 2; ++k) {
        const int y = y0t + yl + k * 16;
        const float* __restrict__ pb = prev + (long)b * IMG + y * W + xb;
        const float4 pr  = *(const float4*)(pb);
        const float4 pgc = *(const float4*)(pb + HW);
        const float4 plc = *(const float4*)(pb + 2 * HW);
        pg[k][0] = 0.299f * pr.x + 0.587f * pgc.x + 0.114f * plc.x;
        pg[k][1] = 0.299f * pr.y + 0.587f * pgc.y + 0.114f * plc.y;
        pg[k][2] = 0.299f * pr.z + 0.587f * pgc.z + 0.114f * plc.z;
        pg[k][3] = 0.299f * pr.w + 0.587f * pgc.w + 0.114f * plc.w;
    }

    __syncthreads();

    const float sxfb = (float)xb * fr;
    const int F  = (int)sxfb;
    const int F2 = min(F + 2, FW - 1);

    double lsum = 0.0;
    unsigned int lcnt = 0;

    #pragma unroll
    for (int k = 0; k < 2; ++k) {
        const int y = y0t + yl + k * 16;

        // flow values (row-shared fy; 3 columns cover the 4 pixels)
        const float syf = (float)y * fr;
        const int   fy0 = (int)syf;
        const float wy  = syf - (float)fy0;
        const int r0 = fy0 - fy_lo;
        const int r1 = min(fy0 + 1, FH - 1) - fy_lo;

        const float* __restrict__ su = smf;
        const float* __restrict__ sv = smf + FROWS * FW;
        const float u0a = su[r0 * FW + F], u0b = su[r0 * FW + F + 1], u0c = su[r0 * FW + F2];
        const float u1a = su[r1 * FW + F], u1b = su[r1 * FW + F + 1], u1c = su[r1 * FW + F2];
        const float v0a = sv[r0 * FW + F], v0b = sv[r0 * FW + F + 1], v0c = sv[r0 * FW + F2];
        const float v1a = sv[r1 * FW + F], v1b = sv[r1 * FW + F + 1], v1c = sv[r1 * FW + F2];

        #pragma unroll
        for (int i = 0; i < 4; ++i) {
            const int x = xb + i;
            const float sxf = (float)x * fr;
            const int   fx0 = (int)sxf;
            const float wx  = sxf - (float)fx0;
            const int   d   = fx0 - F;   // 0 or 1

            const float u00 = d ? u0b : u0a, u01 = d ? u0c : u0b;
            const float u10 = d ? u1b : u1a, u11 = d ? u1c : u1b;
            const float v00 = d ? v0b : v0a, v01 = d ? v0c : v0b;
            const float v10 = d ? v1b : v1a, v11 = d ? v1c : v1b;

            // row-lerp then col-lerp (reference op order), then *4 scale
            const float uc0 = u00 * (1.0f - wy) + u10 * wy;
            const float uc1 = u01 * (1.0f - wy) + u11 * wy;
            const float vc0 = v00 * (1.0f - wy) + v10 * wy;
            const float vc1 = v01 * (1.0f - wy) + v11 * wy;
            const float u = (uc0 * (1.0f - wx) + uc1 * wx) * 4.0f;
            const float v = (vc0 * (1.0f - wx) + vc1 * wx) * 4.0f;

            const float gx = (float)x + u;
            const float gy = (float)y + v;
            const float vm = ((gx >= 0.0f) & (gx <= (float)(W - 1)) &
                              (gy >= 0.0f) & (gy <= (float)(H - 1))) ? 1.0f : 0.0f;

            const float gxf = floorf(gx), gyf = floorf(gy);
            const float wwx = gx - gxf,  wwy = gy - gyf;
            const int ix0 = (int)gxf, iy0 = (int)gyf;

            const int cx = ix0 - (x0t - 24);
            const int ry = iy0 - (y0t - 24);
            float c00, c01, c10, c11;
            if ((unsigned)cx <= (unsigned)(TW - 2) && (unsigned)ry <= (unsigned)(TH - 2)) {
                const int la = ry * TW + cx;
                c00 = (float)smh[la];      c01 = (float)smh[la + 1];
                c10 = (float)smh[la + TW]; c11 = (float)smh[la + TW + 1];
            } else {
                // rare (|disp|>~20 or invalid px): exact per-corner masked gather
                const bool vx0g = (ix0 >= 0) & (ix0 < W);
                const bool vx1g = (ix0 + 1 >= 0) & (ix0 + 1 < W);
                const bool vy0g = (iy0 >= 0) & (iy0 < H);
                const bool vy1g = (iy0 + 1 >= 0) & (iy0 + 1 < H);
                const int xc0 = min(max(ix0, 0), W - 1), xc1 = min(max(ix0 + 1, 0), W - 1);
                const int yc0 = min(max(iy0, 0), H - 1), yc1 = min(max(iy0 + 1, 0), H - 1);
                c00 = (vy0g & vx0g) ? gray3(nb, yc0 * W + xc0) : 0.0f;
                c01 = (vy0g & vx1g) ? gray3(nb, yc0 * W + xc1) : 0.0f;
                c10 = (vy1g & vx0g) ? gray3(nb, yc1 * W + xc0) : 0.0f;
                c11 = (vy1g & vx1g) ? gray3(nb, yc1 * W + xc1) : 0.0f;
            }

            const float warped = c00 * (1.0f - wwx) * (1.0f - wwy)
                               + c01 * wwx * (1.0f - wwy)
                               + c10 * (1.0f - wwx) * wwy
                               + c11 * wwx * wwy;
            const float diff = pg[k][i] - warped;
            const float l = sqrtf(diff * diff + EPS * EPS);
            lsum += (double)(l * vm);
            lcnt += (unsigned int)vm;
        }
    }

    // ---- wave64 + block reduce; ONE partial store per block (no atomics) ----
    #pragma unroll
    for (int off = 32; off > 0; off >>= 1) {
        lsum += __shfl_down(lsum, off);
        lcnt += __shfl_down(lcnt, off);
    }
    __shared__ double s_sum[4];
    __shared__ unsigned int s_cnt[4];
    const int wid = threadIdx.x >> 6, lane = threadIdx.x & 63;
    if (lane == 0) { s_sum[wid] = lsum; s_cnt[wid] = lcnt; }
    __syncthreads();
    if (threadIdx.x == 0) {
        psum[blockIdx.x] = s_sum[0] + s_sum[1] + s_sum[2] + s_sum[3];
        pcnt[blockIdx.x] = s_cnt[0] + s_cnt[1] + s_cnt[2] + s_cnt[3];
    }
}

// ---------------- reduce partials ----------------
__global__ __launch_bounds__(256) void reduce_kernel(
    const double* __restrict__ psum, const unsigned int* __restrict__ pcnt,
    int nb, float* __restrict__ out)
{
    double s = 0.0;
    unsigned long long c = 0;
    for (int i = threadIdx.x; i < nb; i += 256) {
        s += psum[i];
        c += (unsigned long long)pcnt[i];
    }
    #pragma unroll
    for (int off = 32; off > 0; off >>= 1) {
        s += __shfl_down(s, off);
        c += __shfl_down(c, off);
    }
    __shared__ double ss[4];
    __shared__ unsigned long long sc[4];
    const int wid = threadIdx.x >> 6, lane = threadIdx.x & 63;
    if (lane == 0) { ss[wid] = s; sc[wid] = c; }
    __syncthreads();
    if (threadIdx.x == 0) {
        double ts = ss[0] + ss[1] + ss[2] + ss[3];
        double tc = (double)(sc[0] + sc[1] + sc[2] + sc[3]);
        if (tc < 1.0) tc = 1.0;
        const float loss = (float)(ts / tc);
        out[0] = loss;
        out[1] = loss;
    }
}

extern "C" void kernel_launch(void* const* d_in, const int* in_sizes, int n_in,
                              void* d_out, int out_size, void* d_ws, size_t ws_size,
                              hipStream_t stream) {
    const float* prev = (const float*)d_in[0];
    const float* nxt  = (const float*)d_in[1];
    const float* flow = (const float*)d_in[2];
    float* out = (float*)d_out;

    // ws layout: [0, NB*8) double partial sums; [NB*8, NB*12) uint counts.
    double* psum = (double*)d_ws;
    unsigned int* pcnt = (unsigned int*)((char*)d_ws + NB * 8);

    loss_kernel<<<dim3(NB), dim3(256), 0, stream>>>(prev, nxt, flow, psum, pcnt);
    reduce_kernel<<<dim3(1), dim3(256), 0, stream>>>(psum, pcnt, NB, out);
}

// Round 9
// 35.750 us; speedup vs baseline: 1.2313x; 1.2313x over previous
//
#include <hip/hip_runtime.h>

// FlowWarpConsistencyLoss: B=16, C=3, H=W=512, flow 2x128x128.
// Pass 1: grayscale pred_next -> ZERO-PADDED fp16 buffer (576x576/img) in d_ws.
// Pass 2: block = 64x32 tile; stage 104x64 fp16 gray tile (halo 16) + 10x24
//         flow col-window (f32) into LDS (15.4 KB -> 8 blocks/CU); gathers hit
//         LDS; rare out-of-tile -> exact clamped read of zero-padded buffer;
//         per-block partial -> d_ws slot (NO global atomics).
// Pass 3: single-block reduce of 2048 partials -> out.
// R8->R9: ticket/last-block reduce REVERTED (cross-XCD stale reads of partials
//         through per-XCD L2s gave out~0; launch boundary is the reliable
//         device-wide release). Kept halo-16 + flow col-window LDS shrink.

typedef _Float16 half8 __attribute__((ext_vector_type(8)));

constexpr int B  = 16;
constexpr int H  = 512;
constexpr int W  = 512;
constexpr int FH = 128;
constexpr int FW = 128;
constexpr int HW  = H * W;
constexpr int IMG = 3 * HW;
constexpr int FHW = FH * FW;
constexpr float EPS = 0.001f;

constexpr int P    = 32;            // zero padding on every side (pass-1 buffer)
constexpr int PW   = W + 2 * P;     // 576
constexpr int PH   = H + 2 * P;     // 576
constexpr int PIMG = PW * PH;       // halves per padded image
constexpr int PQ8  = PH * (PW / 8); // half8-chunks per padded image

constexpr int TX = 64, TY = 32;     // output tile per block
constexpr int TW = 104, TH = 64;    // staged tile: x [x0t-16,x0t+88), y [y0t-16,y0t+48)
constexpr int FROWS = 10;           // flow rows staged
constexpr int FCOLS = 24;           // flow cols staged (4-aligned window)

constexpr int NB = 2048;            // blocks (16 images x 128 tiles)

// ---------------- pass 1: gray(next) into padded fp16 buffer ----------------
__global__ __launch_bounds__(256) void pad_gray_kernel(
    const float* __restrict__ nxt, _Float16* __restrict__ g)
{
    const int q  = blockIdx.x * 256 + threadIdx.x;   // half8 chunk index
    const int b  = q / PQ8;
    const int r  = q - b * PQ8;
    const int py = r / (PW / 8);
    const int qx = r - py * (PW / 8);
    const int y  = py - P;
    const int xs = qx * 8 - P;
    half8 o = (half8)0;
    if ((unsigned)y < (unsigned)H && (unsigned)xs <= (unsigned)(W - 8)) {
        const float* __restrict__ nb = nxt + (long)b * IMG + y * W + xs;
        #pragma unroll
        for (int h = 0; h < 2; ++h) {
            const float4 rr = *(const float4*)(nb + 4 * h);
            const float4 gg = *(const float4*)(nb + HW + 4 * h);
            const float4 bl = *(const float4*)(nb + 2 * HW + 4 * h);
            o[4 * h + 0] = (_Float16)(0.299f * rr.x + 0.587f * gg.x + 0.114f * bl.x);
            o[4 * h + 1] = (_Float16)(0.299f * rr.y + 0.587f * gg.y + 0.114f * bl.y);
            o[4 * h + 2] = (_Float16)(0.299f * rr.z + 0.587f * gg.z + 0.114f * bl.z);
            o[4 * h + 3] = (_Float16)(0.299f * rr.w + 0.587f * gg.w + 0.114f * bl.w);
        }
    }
    *(half8*)(g + (long)b * PIMG + py * PW + qx * 8) = o;
}

// ---------------- pass 2: LDS-tiled warp + loss, partials out ----------------
__global__ __launch_bounds__(256) void loss_kernel(
    const float* __restrict__ prev, const _Float16* __restrict__ gpad,
    const float* __restrict__ flow, double* __restrict__ psum,
    unsigned int* __restrict__ pcnt)
{
    __shared__ __align__(16) _Float16 smh[TW * TH];           // 13.3 KB
    __shared__ __align__(16) float    smf[2 * FROWS * FCOLS]; // 1.9 KB

    // XCD-chunked: 8 XCDs x 256 contiguous blocks (= 2 images each).
    const int bid = ((blockIdx.x & 7) << 8) | (blockIdx.x >> 3);
    const int b   = bid >> 7;              // 128 tiles per image
    const int t   = bid & 127;
    const int tx  = t & 7;                 // 8 x-tiles (64 wide)
    const int ty  = t >> 3;                // 16 y-tiles (32 tall)
    const int x0t = tx * TX;
    const int y0t = ty * TY;

    const float fr = (float)(127.0 / 511.0);
    const int fy_lo = (int)((float)y0t * fr);
    const int c0    = min((int)((float)x0t * fr) & ~3, FW - FCOLS); // 4-aligned col window

    const _Float16* __restrict__ gb = gpad + (long)b * PIMG;

    // ---- stage gray tile from fp16 padded buffer (uint4 chunks)
    {
        // tile origin (x0t-16, y0t-16) -> padded coords (+P)
        const _Float16* __restrict__ src = gb + (y0t - 16 + P) * PW + (x0t - 16 + P);
        for (int it = threadIdx.x; it < TH * (TW / 8); it += 256) {
            const int r = it / (TW / 8), c = it - r * (TW / 8);
            *(uint4*)(smh + r * TW + c * 8) = *(const uint4*)(src + r * PW + c * 8);
        }
        // ---- stage flow window: FROWS x FCOLS, u then v
        const float* __restrict__ fsrc = flow + (long)b * 2 * FHW;
        for (int it = threadIdx.x; it < 2 * FROWS * (FCOLS / 4); it += 256) {
            const int comp = it / (FROWS * (FCOLS / 4));
            const int rem  = it - comp * (FROWS * (FCOLS / 4));
            const int rr   = rem / (FCOLS / 4);
            const int c4   = rem - rr * (FCOLS / 4);
            const int frow = min(fy_lo + rr, FH - 1);
            const float4 v = *(const float4*)(fsrc + comp * FHW + frow * FW + c0 + c4 * 4);
            *(float4*)(smf + comp * (FROWS * FCOLS) + rr * FCOLS + c4 * 4) = v;
        }
    }

    // ---- prev grayscale: thread = 4 consecutive x in rows yl and yl+16
    const int xq = threadIdx.x & 15;
    const int yl = threadIdx.x >> 4;
    const int xb = x0t + xq * 4;

    float pg[2][4];
    #pragma unroll
    for (int k = 0; k < 2; ++k) {
        const int y = y0t + yl + k * 16;
        const float* __restrict__ pb = prev + (long)b * IMG + y * W + xb;
        const float4 pr  = *(const float4*)(pb);
        const float4 pgc = *(const float4*)(pb + HW);
        const float4 plc = *(const float4*)(pb + 2 * HW);
        pg[k][0] = 0.299f * pr.x + 0.587f * pgc.x + 0.114f * plc.x;
        pg[k][1] = 0.299f * pr.y + 0.587f * pgc.y + 0.114f * plc.y;
        pg[k][2] = 0.299f * pr.z + 0.587f * pgc.z + 0.114f * plc.z;
        pg[k][3] = 0.299f * pr.w + 0.587f * pgc.w + 0.114f * plc.w;
    }

    __syncthreads();

    const float sxfb = (float)xb * fr;
    const int F   = (int)sxfb;          // floor (x >= 0)
    const int Fl  = F - c0;             // local col of F
    const int F2l = min(F + 2, FW - 1) - c0;

    double lsum = 0.0;
    unsigned int lcnt = 0;

    #pragma unroll
    for (int k = 0; k < 2; ++k) {
        const int y = y0t + yl + k * 16;

        const float syf = (float)y * fr;
        const int   fy0 = (int)syf;
        const float wy  = syf - (float)fy0;
        const int r0 = fy0 - fy_lo;
        const int r1 = min(fy0 + 1, FH - 1) - fy_lo;

        const float* __restrict__ su = smf;
        const float* __restrict__ sv = smf + FROWS * FCOLS;
        const float u0a = su[r0 * FCOLS + Fl], u0b = su[r0 * FCOLS + Fl + 1], u0c = su[r0 * FCOLS + F2l];
        const float u1a = su[r1 * FCOLS + Fl], u1b = su[r1 * FCOLS + Fl + 1], u1c = su[r1 * FCOLS + F2l];
        const float v0a = sv[r0 * FCOLS + Fl], v0b = sv[r0 * FCOLS + Fl + 1], v0c = sv[r0 * FCOLS + F2l];
        const float v1a = sv[r1 * FCOLS + Fl], v1b = sv[r1 * FCOLS + Fl + 1], v1c = sv[r1 * FCOLS + F2l];

        #pragma unroll
        for (int i = 0; i < 4; ++i) {
            const int x = xb + i;
            const float sxf = (float)x * fr;
            const int   fx0 = (int)sxf;
            const float wx  = sxf - (float)fx0;
            const int   d   = fx0 - F;   // 0 or 1

            const float u00 = d ? u0b : u0a, u01 = d ? u0c : u0b;
            const float u10 = d ? u1b : u1a, u11 = d ? u1c : u1b;
            const float v00 = d ? v0b : v0a, v01 = d ? v0c : v0b;
            const float v10 = d ? v1b : v1a, v11 = d ? v1c : v1b;

            // row-lerp then col-lerp (reference op order), then *4 scale
            const float uc0 = u00 * (1.0f - wy) + u10 * wy;
            const float uc1 = u01 * (1.0f - wy) + u11 * wy;
            const float vc0 = v00 * (1.0f - wy) + v10 * wy;
            const float vc1 = v01 * (1.0f - wy) + v11 * wy;
            const float u = (uc0 * (1.0f - wx) + uc1 * wx) * 4.0f;
            const float v = (vc0 * (1.0f - wx) + vc1 * wx) * 4.0f;

            const float gx = (float)x + u;
            const float gy = (float)y + v;
            const float vm = ((gx >= 0.0f) & (gx <= (float)(W - 1)) &
                              (gy >= 0.0f) & (gy <= (float)(H - 1))) ? 1.0f : 0.0f;

            const float gxf = floorf(gx), gyf = floorf(gy);
            const float wwx = gx - gxf,  wwy = gy - gyf;
            const int ix0 = (int)gxf, iy0 = (int)gyf;

            const int cx = ix0 - (x0t - 16);
            const int ry = iy0 - (y0t - 16);
            float c00, c01, c10, c11;
            if ((unsigned)cx <= (unsigned)(TW - 2) && (unsigned)ry <= (unsigned)(TH - 2)) {
                const int la = ry * TW + cx;
                c00 = (float)smh[la];      c01 = (float)smh[la + 1];
                c10 = (float)smh[la + TW]; c11 = (float)smh[la + TW + 1];
            } else {
                // rare: clamp into padded buffer. Clamped coords land in the
                // zero pad exactly matching reference per-corner zeroing.
                const int iyc = min(max(iy0, -P), PH - P - 2);
                const int ixc = min(max(ix0, -P), PW - P - 2);
                const _Float16* __restrict__ gp = gb + (iyc + P) * PW + (ixc + P);
                c00 = (float)gp[0];  c01 = (float)gp[1];
                c10 = (float)gp[PW]; c11 = (float)gp[PW + 1];
            }

            const float warped = c00 * (1.0f - wwx) * (1.0f - wwy)
                               + c01 * wwx * (1.0f - wwy)
                               + c10 * (1.0f - wwx) * wwy
                               + c11 * wwx * wwy;
            const float diff = pg[k][i] - warped;
            const float l = sqrtf(diff * diff + EPS * EPS);
            lsum += (double)(l * vm);
            lcnt += (unsigned int)vm;
        }
    }

    // ---- wave64 + block reduce; ONE partial store per block ----
    #pragma unroll
    for (int off = 32; off > 0; off >>= 1) {
        lsum += __shfl_down(lsum, off);
        lcnt += __shfl_down(lcnt, off);
    }
    __shared__ double s_sum[4];
    __shared__ unsigned int s_cnt[4];
    const int wid = threadIdx.x >> 6, lane = threadIdx.x & 63;
    if (lane == 0) { s_sum[wid] = lsum; s_cnt[wid] = lcnt; }
    __syncthreads();
    if (threadIdx.x == 0) {
        psum[blockIdx.x] = s_sum[0] + s_sum[1] + s_sum[2] + s_sum[3];
        pcnt[blockIdx.x] = s_cnt[0] + s_cnt[1] + s_cnt[2] + s_cnt[3];
    }
}

// ---------------- pass 3: reduce partials ----------------
__global__ __launch_bounds__(256) void reduce_kernel(
    const double* __restrict__ psum, const unsigned int* __restrict__ pcnt,
    float* __restrict__ out)
{
    double s = 0.0;
    unsigned long long c = 0;
    for (int i = threadIdx.x; i < NB; i += 256) {
        s += psum[i];
        c += (unsigned long long)pcnt[i];
    }
    #pragma unroll
    for (int off = 32; off > 0; off >>= 1) {
        s += __shfl_down(s, off);
        c += __shfl_down(c, off);
    }
    __shared__ double ss[4];
    __shared__ unsigned long long sc[4];
    const int wid = threadIdx.x >> 6, lane = threadIdx.x & 63;
    if (lane == 0) { ss[wid] = s; sc[wid] = c; }
    __syncthreads();
    if (threadIdx.x == 0) {
        const double ts = ss[0] + ss[1] + ss[2] + ss[3];
        double tc = (double)(sc[0] + sc[1] + sc[2] + sc[3]);
        if (tc < 1.0) tc = 1.0;
        const float loss = (float)(ts / tc);
        out[0] = loss;
        out[1] = loss;
    }
}

extern "C" void kernel_launch(void* const* d_in, const int* in_sizes, int n_in,
                              void* d_out, int out_size, void* d_ws, size_t ws_size,
                              hipStream_t stream) {
    const float* prev = (const float*)d_in[0];
    const float* nxt  = (const float*)d_in[1];
    const float* flow = (const float*)d_in[2];
    float* out = (float*)d_out;

    // ws layout: [0, NB*8) f64 partial sums; [NB*8, NB*12) uint counts;
    //            [32768, ...) padded fp16 gray buffer (10.6 MB)
    double* psum = (double*)d_ws;
    unsigned int* pcnt = (unsigned int*)((char*)d_ws + NB * 8);
    _Float16* gbuf = (_Float16*)((char*)d_ws + 32768);

    pad_gray_kernel<<<dim3(B * PQ8 / 256), dim3(256), 0, stream>>>(nxt, gbuf);
    loss_kernel<<<dim3(NB), dim3(256), 0, stream>>>(prev, gbuf, flow, psum, pcnt);
    reduce_kernel<<<dim3(1), dim3(256), 0, stream>>>(psum, pcnt, out);
}

// Round 11
// 35.033 us; speedup vs baseline: 1.2564x; 1.0204x over previous
//
#include <hip/hip_runtime.h>

// FlowWarpConsistencyLoss: B=16, C=3, H=W=512, flow 2x128x128.
// Pass 1: grayscale pred_next -> ZERO-PADDED fp16 buffer (576x576/img) in d_ws.
//         XCD-ALIGNED: XCD k (blockIdx%8) writes images 2k,2k+1 -- the same
//         images XCD k's loss blocks read -> gray staging hits local L2
//         (1.3 MB/XCD working set << 4 MiB per-XCD L2).
// Pass 2: block = 64x32 tile; stage 104x64 fp16 gray tile (halo 16) + 10x24
//         flow col-window (f32) into LDS (15.4 KB -> 8 blocks/CU); gathers hit
//         LDS; rare out-of-tile -> exact clamped read of zero-padded buffer;
//         per-block partial -> d_ws slot (NO global atomics).
// Pass 3: single-block reduce of 2048 partials -> out.
// R10->R11: ticket/last-block reduce ABANDONED (2x cross-XCD stale-partials
//         failures, even with AGENT-scope atomics). 3-launch structure is the
//         proven design; kept only R10's output-identical XCD-aligned pad_gray.

typedef _Float16 half8 __attribute__((ext_vector_type(8)));

constexpr int B  = 16;
constexpr int H  = 512;
constexpr int W  = 512;
constexpr int FH = 128;
constexpr int FW = 128;
constexpr int HW  = H * W;
constexpr int IMG = 3 * HW;
constexpr int FHW = FH * FW;
constexpr float EPS = 0.001f;

constexpr int P    = 32;            // zero padding on every side (pass-1 buffer)
constexpr int PW   = W + 2 * P;     // 576
constexpr int PH   = H + 2 * P;     // 576
constexpr int PIMG = PW * PH;       // halves per padded image
constexpr int PQ8  = PH * (PW / 8); // half8-chunks per padded image (41472)

constexpr int TX = 64, TY = 32;     // output tile per block
constexpr int TW = 104, TH = 64;    // staged tile: x [x0t-16,x0t+88), y [y0t-16,y0t+48)
constexpr int FROWS = 10;           // flow rows staged
constexpr int FCOLS = 24;           // flow cols staged (4-aligned window)

constexpr int NB  = 2048;           // blocks in loss (16 images x 128 tiles)
constexpr int NPG = B * PQ8 / 256;  // 2592 pad_gray blocks (= 8 x 324)

// ---------------- pass 1: gray(next) into padded fp16 buffer ----------------
__global__ __launch_bounds__(256) void pad_gray_kernel(
    const float* __restrict__ nxt, _Float16* __restrict__ g)
{
    // XCD-aligned chunking: XCD k (= blockIdx%8) handles chunk-blocks
    // [324k, 324k+324) = images 2k, 2k+1 (162 blocks/image). Output-identical
    // to the linear map; only the block->data assignment changes.
    const int j   = blockIdx.x;
    const int q   = (((j & 7) * (NPG / 8)) + (j >> 3)) * 256 + threadIdx.x;
    const int b   = q / PQ8;
    const int r   = q - b * PQ8;
    const int py  = r / (PW / 8);
    const int qx  = r - py * (PW / 8);
    const int y   = py - P;
    const int xs  = qx * 8 - P;
    half8 o = (half8)0;
    if ((unsigned)y < (unsigned)H && (unsigned)xs <= (unsigned)(W - 8)) {
        const float* __restrict__ nb = nxt + (long)b * IMG + y * W + xs;
        #pragma unroll
        for (int h = 0; h < 2; ++h) {
            const float4 rr = *(const float4*)(nb + 4 * h);
            const float4 gg = *(const float4*)(nb + HW + 4 * h);
            const float4 bl = *(const float4*)(nb + 2 * HW + 4 * h);
            o[4 * h + 0] = (_Float16)(0.299f * rr.x + 0.587f * gg.x + 0.114f * bl.x);
            o[4 * h + 1] = (_Float16)(0.299f * rr.y + 0.587f * gg.y + 0.114f * bl.y);
            o[4 * h + 2] = (_Float16)(0.299f * rr.z + 0.587f * gg.z + 0.114f * bl.z);
            o[4 * h + 3] = (_Float16)(0.299f * rr.w + 0.587f * gg.w + 0.114f * bl.w);
        }
    }
    *(half8*)(g + (long)b * PIMG + py * PW + qx * 8) = o;
}

// ---------------- pass 2: LDS-tiled warp + loss, partials out ----------------
__global__ __launch_bounds__(256) void loss_kernel(
    const float* __restrict__ prev, const _Float16* __restrict__ gpad,
    const float* __restrict__ flow, double* __restrict__ psum,
    unsigned int* __restrict__ pcnt)
{
    __shared__ __align__(16) _Float16 smh[TW * TH];           // 13.3 KB
    __shared__ __align__(16) float    smf[2 * FROWS * FCOLS]; // 1.9 KB

    // XCD-chunked: 8 XCDs x 256 contiguous blocks (= 2 images each).
    const int bid = ((blockIdx.x & 7) << 8) | (blockIdx.x >> 3);
    const int b   = bid >> 7;              // 128 tiles per image
    const int t   = bid & 127;
    const int tx  = t & 7;                 // 8 x-tiles (64 wide)
    const int ty  = t >> 3;                // 16 y-tiles (32 tall)
    const int x0t = tx * TX;
    const int y0t = ty * TY;

    const float fr = (float)(127.0 / 511.0);
    const int fy_lo = (int)((float)y0t * fr);
    const int c0    = min((int)((float)x0t * fr) & ~3, FW - FCOLS); // 4-aligned col window

    const _Float16* __restrict__ gb = gpad + (long)b * PIMG;

    // ---- stage gray tile from fp16 padded buffer (uint4 chunks)
    {
        // tile origin (x0t-16, y0t-16) -> padded coords (+P)
        const _Float16* __restrict__ src = gb + (y0t - 16 + P) * PW + (x0t - 16 + P);
        for (int it = threadIdx.x; it < TH * (TW / 8); it += 256) {
            const int r = it / (TW / 8), c = it - r * (TW / 8);
            *(uint4*)(smh + r * TW + c * 8) = *(const uint4*)(src + r * PW + c * 8);
        }
        // ---- stage flow window: FROWS x FCOLS, u then v
        const float* __restrict__ fsrc = flow + (long)b * 2 * FHW;
        for (int it = threadIdx.x; it < 2 * FROWS * (FCOLS / 4); it += 256) {
            const int comp = it / (FROWS * (FCOLS / 4));
            const int rem  = it - comp * (FROWS * (FCOLS / 4));
            const int rr   = rem / (FCOLS / 4);
            const int c4   = rem - rr * (FCOLS / 4);
            const int frow = min(fy_lo + rr, FH - 1);
            const float4 v = *(const float4*)(fsrc + comp * FHW + frow * FW + c0 + c4 * 4);
            *(float4*)(smf + comp * (FROWS * FCOLS) + rr * FCOLS + c4 * 4) = v;
        }
    }

    // ---- prev grayscale: thread = 4 consecutive x in rows yl and yl+16
    const int xq = threadIdx.x & 15;
    const int yl = threadIdx.x >> 4;
    const int xb = x0t + xq * 4;

    float pg[2][4];
    #pragma unroll
    for (int k = 0; k < 2; ++k) {
        const int y = y0t + yl + k * 16;
        const float* __restrict__ pb = prev + (long)b * IMG + y * W + xb;
        const float4 pr  = *(const float4*)(pb);
        const float4 pgc = *(const float4*)(pb + HW);
        const float4 plc = *(const float4*)(pb + 2 * HW);
        pg[k][0] = 0.299f * pr.x + 0.587f * pgc.x + 0.114f * plc.x;
        pg[k][1] = 0.299f * pr.y + 0.587f * pgc.y + 0.114f * plc.y;
        pg[k][2] = 0.299f * pr.z + 0.587f * pgc.z + 0.114f * plc.z;
        pg[k][3] = 0.299f * pr.w + 0.587f * pgc.w + 0.114f * plc.w;
    }

    __syncthreads();

    const float sxfb = (float)xb * fr;
    const int F   = (int)sxfb;          // floor (x >= 0)
    const int Fl  = F - c0;             // local col of F
    const int F2l = min(F + 2, FW - 1) - c0;

    double lsum = 0.0;
    unsigned int lcnt = 0;

    #pragma unroll
    for (int k = 0; k < 2; ++k) {
        const int y = y0t + yl + k * 16;

        const float syf = (float)y * fr;
        const int   fy0 = (int)syf;
        const float wy  = syf - (float)fy0;
        const int r0 = fy0 - fy_lo;
        const int r1 = min(fy0 + 1, FH - 1) - fy_lo;

        const float* __restrict__ su = smf;
        const float* __restrict__ sv = smf + FROWS * FCOLS;
        const float u0a = su[r0 * FCOLS + Fl], u0b = su[r0 * FCOLS + Fl + 1], u0c = su[r0 * FCOLS + F2l];
        const float u1a = su[r1 * FCOLS + Fl], u1b = su[r1 * FCOLS + Fl + 1], u1c = su[r1 * FCOLS + F2l];
        const float v0a = sv[r0 * FCOLS + Fl], v0b = sv[r0 * FCOLS + Fl + 1], v0c = sv[r0 * FCOLS + F2l];
        const float v1a = sv[r1 * FCOLS + Fl], v1b = sv[r1 * FCOLS + Fl + 1], v1c = sv[r1 * FCOLS + F2l];

        #pragma unroll
        for (int i = 0; i < 4; ++i) {
            const int x = xb + i;
            const float sxf = (float)x * fr;
            const int   fx0 = (int)sxf;
            const float wx  = sxf - (float)fx0;
            const int   d   = fx0 - F;   // 0 or 1

            const float u00 = d ? u0b : u0a, u01 = d ? u0c : u0b;
            const float u10 = d ? u1b : u1a, u11 = d ? u1c : u1b;
            const float v00 = d ? v0b : v0a, v01 = d ? v0c : v0b;
            const float v10 = d ? v1b : v1a, v11 = d ? v1c : v1b;

            // row-lerp then col-lerp (reference op order), then *4 scale
            const float uc0 = u00 * (1.0f - wy) + u10 * wy;
            const float uc1 = u01 * (1.0f - wy) + u11 * wy;
            const float vc0 = v00 * (1.0f - wy) + v10 * wy;
            const float vc1 = v01 * (1.0f - wy) + v11 * wy;
            const float u = (uc0 * (1.0f - wx) + uc1 * wx) * 4.0f;
            const float v = (vc0 * (1.0f - wx) + vc1 * wx) * 4.0f;

            const float gx = (float)x + u;
            const float gy = (float)y + v;
            const float vm = ((gx >= 0.0f) & (gx <= (float)(W - 1)) &
                              (gy >= 0.0f) & (gy <= (float)(H - 1))) ? 1.0f : 0.0f;

            const float gxf = floorf(gx), gyf = floorf(gy);
            const float wwx = gx - gxf,  wwy = gy - gyf;
            const int ix0 = (int)gxf, iy0 = (int)gyf;

            const int cx = ix0 - (x0t - 16);
            const int ry = iy0 - (y0t - 16);
            float c00, c01, c10, c11;
            if ((unsigned)cx <= (unsigned)(TW - 2) && (unsigned)ry <= (unsigned)(TH - 2)) {
                const int la = ry * TW + cx;
                c00 = (float)smh[la];      c01 = (float)smh[la + 1];
                c10 = (float)smh[la + TW]; c11 = (float)smh[la + TW + 1];
            } else {
                // rare: clamp into padded buffer. Clamped coords land in the
                // zero pad exactly matching reference per-corner zeroing.
                const int iyc = min(max(iy0, -P), PH - P - 2);
                const int ixc = min(max(ix0, -P), PW - P - 2);
                const _Float16* __restrict__ gp = gb + (iyc + P) * PW + (ixc + P);
                c00 = (float)gp[0];  c01 = (float)gp[1];
                c10 = (float)gp[PW]; c11 = (float)gp[PW + 1];
            }

            const float warped = c00 * (1.0f - wwx) * (1.0f - wwy)
                               + c01 * wwx * (1.0f - wwy)
                               + c10 * (1.0f - wwx) * wwy
                               + c11 * wwx * wwy;
            const float diff = pg[k][i] - warped;
            const float l = sqrtf(diff * diff + EPS * EPS);
            lsum += (double)(l * vm);
            lcnt += (unsigned int)vm;
        }
    }

    // ---- wave64 + block reduce; ONE partial store per block ----
    #pragma unroll
    for (int off = 32; off > 0; off >>= 1) {
        lsum += __shfl_down(lsum, off);
        lcnt += __shfl_down(lcnt, off);
    }
    __shared__ double s_sum[4];
    __shared__ unsigned int s_cnt[4];
    const int wid = threadIdx.x >> 6, lane = threadIdx.x & 63;
    if (lane == 0) { s_sum[wid] = lsum; s_cnt[wid] = lcnt; }
    __syncthreads();
    if (threadIdx.x == 0) {
        psum[blockIdx.x] = s_sum[0] + s_sum[1] + s_sum[2] + s_sum[3];
        pcnt[blockIdx.x] = s_cnt[0] + s_cnt[1] + s_cnt[2] + s_cnt[3];
    }
}

// ---------------- pass 3: reduce partials ----------------
__global__ __launch_bounds__(256) void reduce_kernel(
    const double* __restrict__ psum, const unsigned int* __restrict__ pcnt,
    float* __restrict__ out)
{
    double s = 0.0;
    unsigned long long c = 0;
    for (int i = threadIdx.x; i < NB; i += 256) {
        s += psum[i];
        c += (unsigned long long)pcnt[i];
    }
    #pragma unroll
    for (int off = 32; off > 0; off >>= 1) {
        s += __shfl_down(s, off);
        c += __shfl_down(c, off);
    }
    __shared__ double ss[4];
    __shared__ unsigned long long sc[4];
    const int wid = threadIdx.x >> 6, lane = threadIdx.x & 63;
    if (lane == 0) { ss[wid] = s; sc[wid] = c; }
    __syncthreads();
    if (threadIdx.x == 0) {
        const double ts = ss[0] + ss[1] + ss[2] + ss[3];
        double tc = (double)(sc[0] + sc[1] + sc[2] + sc[3]);
        if (tc < 1.0) tc = 1.0;
        const float loss = (float)(ts / tc);
        out[0] = loss;
        out[1] = loss;
    }
}

extern "C" void kernel_launch(void* const* d_in, const int* in_sizes, int n_in,
                              void* d_out, int out_size, void* d_ws, size_t ws_size,
                              hipStream_t stream) {
    const float* prev = (const float*)d_in[0];
    const float* nxt  = (const float*)d_in[1];
    const float* flow = (const float*)d_in[2];
    float* out = (float*)d_out;

    // ws layout: [0, NB*8) f64 partial sums; [NB*8, NB*12) uint counts;
    //            [32768, ...) padded fp16 gray buffer (10.6 MB)
    double* psum = (double*)d_ws;
    unsigned int* pcnt = (unsigned int*)((char*)d_ws + NB * 8);
    _Float16* gbuf = (_Float16*)((char*)d_ws + 32768);

    pad_gray_kernel<<<dim3(NPG), dim3(256), 0, stream>>>(nxt, gbuf);
    loss_kernel<<<dim3(NB), dim3(256), 0, stream>>>(prev, gbuf, flow, psum, pcnt);
    reduce_kernel<<<dim3(1), dim3(256), 0, stream>>>(psum, pcnt, out);
}